// Round 11
// baseline (96.969 us; speedup 1.0000x reference)
//
#include <hip/hip_runtime.h>
#include <hip/hip_bf16.h>
#include <stdint.h>

#define B_ 8
#define C_ 2048
#define E_ 1024
#define H_ 128
#define M_ (B_*C_)      // 16384 rows total
#define SLOTS_B 144     // chunks per batch: sum_j ceil((j+1)/4), j<32

typedef __attribute__((ext_vector_type(8))) short bf16x8;
typedef __attribute__((ext_vector_type(4))) float f32x4;

__device__ __forceinline__ unsigned short f2bf(float f) {
    union { float f; unsigned int u; } v; v.f = f;
    unsigned int u = v.u;
    u += 0x7fff + ((u >> 16) & 1);   // RNE
    return (unsigned short)(u >> 16);
}
__device__ __forceinline__ float bf2f(unsigned short u) {
    union { unsigned int i; float f; } v; v.i = ((unsigned int)u) << 16; return v.f;
}
// pack two floats -> two bf16 (round-half-up) in ONE v_perm + 2 adds
__device__ __forceinline__ unsigned int pack2bf(float lo, float hi) {
    union { float f; unsigned int u; } a, b; a.f = lo; b.f = hi;
    return __builtin_amdgcn_perm(b.u + 0x8000u, a.u + 0x8000u, 0x07060302);
}

#define GLOAD_LDS16(g, l) \
    __builtin_amdgcn_global_load_lds((const __attribute__((address_space(1))) void*)(g), \
                                     (__attribute__((address_space(3))) void*)(l), 16, 0, 0)

// ---------------- W transpose+convert: (E,H) f32 -> (H,E) bf16, x3 ----------
__global__ __launch_bounds__(256) void wt_kernel(const float* __restrict__ Wq,
                                                 const float* __restrict__ Wk,
                                                 const float* __restrict__ Wv,
                                                 unsigned short* __restrict__ WT) {
    int z = blockIdx.y;
    const float* W = (z == 0) ? Wq : (z == 1) ? Wk : Wv;
    unsigned short* o = WT + (size_t)z * H_ * E_;
    int idx = blockIdx.x * 256 + threadIdx.x;   // over H*E = 131072
    int e = idx & (E_ - 1), h = idx >> 10;
    o[(size_t)h * E_ + e] = f2bf(W[(size_t)e * H_ + h]);
}

// ------ fused-per-W QKV projection: BM=128 BN=128 BK=64, m97-style ----------
// A: reg-stage+convert (intra-step liveness only); B: global_load_lds.
// blockIdx.y = matrix (0=Q,1=K,2=V). V written TRANSPOSED [b][h][c].
#define MF(a, b, c) __builtin_amdgcn_mfma_f32_16x16x32_bf16((a), (b), (c), 0, 0, 0)

__global__ __launch_bounds__(256) void proj_kernel(const float* __restrict__ x,
                                                   const unsigned short* __restrict__ WT,
                                                   unsigned short* __restrict__ QKV) {
    __shared__ __align__(16) unsigned short As[2][128][64];   // 32 KB dbuf, XOR-swz
    __shared__ __align__(16) unsigned short Bs[2][128][64];   // 32 KB dbuf, XOR-swz

    const int tid = threadIdx.x;
    const int wid = tid >> 6, lane = tid & 63;
    const int lrow = lane & 15, lq = lane >> 4;
    const int wr = wid >> 1, wc = wid & 1;       // wave tile: 64 rows x 64 cols
    const int row0 = blockIdx.x * 128;
    const int w = blockIdx.y;
    const unsigned short* wt = WT + (size_t)w * H_ * E_;

    const int arow = tid >> 1;           // A staging row 0..127
    const int ag0 = (tid & 1) * 4;       // first of 4 granules (32 floats/thread)
    const float* xrow = x + (size_t)(row0 + arow) * E_ + ag0 * 8;

    f32x4 acc[4][4];
#pragma unroll
    for (int mi = 0; mi < 4; ++mi)
#pragma unroll
        for (int ni = 0; ni < 4; ++ni) acc[mi][ni] = (f32x4){0.f, 0.f, 0.f, 0.f};

    float4 a4[8];
    auto ALOAD = [&](int t) {
#pragma unroll
        for (int i = 0; i < 8; ++i)
            a4[i] = *(const float4*)(xrow + t * 64 + i * 4);
    };
    auto AWRITE = [&](int buf) {
#pragma unroll
        for (int gi = 0; gi < 4; ++gi) {
            unsigned int t_[4] = {pack2bf(a4[gi*2].x,   a4[gi*2].y),
                                  pack2bf(a4[gi*2].z,   a4[gi*2].w),
                                  pack2bf(a4[gi*2+1].x, a4[gi*2+1].y),
                                  pack2bf(a4[gi*2+1].z, a4[gi*2+1].w)};
            *(uint4*)&As[buf][arow][((ag0 + gi) ^ (arow & 7)) * 8] = *(const uint4*)t_;
        }
    };
    auto BSTAGE = [&](int buf, int t) {   // gload_lds, linear dest + pre-swz source
#pragma unroll
        for (int s = 0; s < 4; ++s) {
            int brow = s * 32 + (tid >> 3);
            int bg = (tid & 7) ^ (brow & 7);
            GLOAD_LDS16(wt + (size_t)brow * E_ + t * 64 + bg * 8,
                        (char*)&Bs[buf][0][0] + s * 4096 + tid * 16);
        }
    };
    auto COMPUTE = [&](int buf) {
#pragma unroll
        for (int ks = 0; ks < 2; ++ks) {
            const int g = ks * 4 + lq;
            bf16x8 af[4], bfr[4];
#pragma unroll
            for (int mi = 0; mi < 4; ++mi) {
                int ra = wr * 64 + mi * 16 + lrow;
                af[mi] = *(const bf16x8*)&As[buf][ra][(g ^ (ra & 7)) * 8];
            }
#pragma unroll
            for (int ni = 0; ni < 4; ++ni) {
                int rb = wc * 64 + ni * 16 + lrow;
                bfr[ni] = *(const bf16x8*)&Bs[buf][rb][(g ^ (rb & 7)) * 8];
            }
#pragma unroll
            for (int mi = 0; mi < 4; ++mi)
#pragma unroll
                for (int ni = 0; ni < 4; ++ni)
                    acc[mi][ni] = MF(af[mi], bfr[ni], acc[mi][ni]);
        }
    };

    // prologue: tile 0 fully staged
    ALOAD(0);
    BSTAGE(0, 0);
    AWRITE(0);

    for (int t = 0; t < 15; ++t) {
        const int cur = t & 1;
        __syncthreads();            // tile t resident; prev reads of buf cur^1 done
        ALOAD(t + 1);               // issue early; consumed by AWRITE below
        BSTAGE(cur ^ 1, t + 1);     // fire-and-forget; lands before next barrier
        COMPUTE(cur);
        AWRITE(cur ^ 1);
    }
    __syncthreads();
    COMPUTE(1);                     // t = 15

    // epilogue: Q (scaled 1/32), K row-major; V transposed [b][h][c]
    if (w < 2) {
        const float qs = (w == 0) ? 0.03125f : 1.0f;   // fold 1/sqrt(E) into Q
        unsigned short* outp = QKV + (size_t)w * M_ * H_;
#pragma unroll
        for (int mi = 0; mi < 4; ++mi) {
            int r0 = row0 + wr * 64 + mi * 16 + lq * 4;
#pragma unroll
            for (int ni = 0; ni < 4; ++ni) {
                int col = wc * 64 + ni * 16 + lrow;
#pragma unroll
                for (int r = 0; r < 4; ++r)
                    outp[(size_t)(r0 + r) * H_ + col] = f2bf(acc[mi][ni][r] * qs);
            }
        }
    } else {
        unsigned short* vt = QKV + (size_t)2 * M_ * H_;
        int b = row0 / C_;
        int cbase = row0 % C_;
#pragma unroll
        for (int mi = 0; mi < 4; ++mi) {
            int c0 = cbase + wr * 64 + mi * 16 + lq * 4;
#pragma unroll
            for (int ni = 0; ni < 4; ++ni) {
                int h = wc * 64 + ni * 16 + lrow;
                __align__(8) unsigned short p[4] = {f2bf(acc[mi][ni][0]), f2bf(acc[mi][ni][1]),
                                                    f2bf(acc[mi][ni][2]), f2bf(acc[mi][ni][3])};
                *(uint2*)&vt[((size_t)b * H_ + h) * C_ + c0] = *(const uint2*)p;
            }
        }
    }
}

// ---------------- split-KV flash attention chunks ---------------------------
// grid (B, 144): blockIdx.x = batch -> XCD = b (K/V L2-resident per XCD)
__global__ __launch_bounds__(256) void attn_kernel(const unsigned short* __restrict__ QKV,
                                                   unsigned short* __restrict__ PO,
                                                   float* __restrict__ ML,
                                                   float* __restrict__ out) {
    __shared__ __align__(16) unsigned short Ks[2][64][128];
    __shared__ __align__(16) unsigned short Vt[2][128][64];
    __shared__ __align__(16) unsigned short Ps[4][16][72];

    const unsigned short* Q  = QKV;
    const unsigned short* K  = QKV + (size_t)M_ * H_;
    const unsigned short* VT = QKV + (size_t)2 * M_ * H_;

    const int tid = threadIdx.x, wid = tid >> 6, lane = tid & 63;
    const int lrow = lane & 15, lq = lane >> 4, lk = lq * 8;
    const int b = blockIdx.x;           // XCD-pinned: linear id % 8 == b
    const int rr = blockIdx.y;          // 0..143

    // decode rr -> (j, c): C(j) = j + 2q(q-1) + s*q, q=j>>2, s=j&3
    int j = 0;
#pragma unroll
    for (int jj = 1; jj < 32; ++jj) {
        int q = jj >> 2, s = jj & 3;
        if (jj + 2 * q * (q - 1) + s * q <= rr) j = jj;
    }
    const int qj = j >> 2, sj = j & 3;
    const int Cj = j + 2 * qj * (qj - 1) + sj * qj;
    const int c = rr - Cj;
    const int nch = qj + 1;
    const int t0 = c * 4;
    const int t1 = min(t0 + 4, j + 1);

    const int q0w = j * 64 + wid * 16;
    const unsigned short* Kb  = K  + (size_t)b * C_ * H_;
    const unsigned short* VTb = VT + (size_t)b * H_ * C_;
    const int qrow0 = q0w + lq * 4;

    const int krow = tid >> 4, kg = tid & 15;
    const int vrow = tid >> 3, vg = tid & 7;

    bf16x8 qf[4];
#pragma unroll
    for (int kf = 0; kf < 4; ++kf)
        qf[kf] = *(const bf16x8*)&Q[((size_t)b * C_ + q0w + lrow) * H_ + kf * 32 + lk];

    f32x4 o[8];
#pragma unroll
    for (int nf = 0; nf < 8; ++nf) o[nf] = (f32x4){0.f, 0.f, 0.f, 0.f};
    float m[4] = {-INFINITY, -INFINITY, -INFINITY, -INFINITY};
    float l[4] = {0.f, 0.f, 0.f, 0.f};

    auto STAGE = [&](int buf, int t) {
        const int kv0 = t * 64;
#pragma unroll
        for (int s = 0; s < 4; ++s) {
            int r = s * 16 + krow;
            GLOAD_LDS16(&Kb[(size_t)(kv0 + r) * H_ + ((kg ^ (r & 15)) * 8)],
                        (char*)&Ks[buf][0][0] + s * 4096 + tid * 16);
        }
#pragma unroll
        for (int s = 0; s < 4; ++s) {
            int h = s * 32 + vrow;
            GLOAD_LDS16(&VTb[(size_t)h * C_ + kv0 + ((vg ^ (h & 7)) * 8)],
                        (char*)&Vt[buf][0][0] + s * 4096 + tid * 16);
        }
    };

    STAGE(0, t0);

    for (int t = t0; t < t1; ++t) {
        const int cur = (t - t0) & 1;
        __syncthreads();
        if (t + 1 < t1) STAGE(cur ^ 1, t + 1);

        const int kv0 = t * 64;
        f32x4 s[4];
        __builtin_amdgcn_s_setprio(1);
#pragma unroll
        for (int nf = 0; nf < 4; ++nf) {
            s[nf] = (f32x4){0.f, 0.f, 0.f, 0.f};
            const int rk = nf * 16 + lrow;
#pragma unroll
            for (int kf = 0; kf < 4; ++kf) {
                bf16x8 kb = *(const bf16x8*)&Ks[cur][rk][((kf * 4 + lq) ^ (rk & 15)) * 8];
                s[nf] = __builtin_amdgcn_mfma_f32_16x16x32_bf16(qf[kf], kb, s[nf], 0, 0, 0);
            }
        }
        __builtin_amdgcn_s_setprio(0);
        bf16x8 vb[8][2];
#pragma unroll
        for (int nf = 0; nf < 8; ++nf) {
            const int h = nf * 16 + lrow;
#pragma unroll
            for (int kf2 = 0; kf2 < 2; ++kf2)
                vb[nf][kf2] = *(const bf16x8*)&Vt[cur][h][((kf2 * 4 + lq) ^ (h & 7)) * 8];
        }

        if (t == j) {
#pragma unroll
            for (int nf = 0; nf < 4; ++nf) {
                int key = kv0 + nf * 16 + lrow;
#pragma unroll
                for (int r = 0; r < 4; ++r)
                    if (key > qrow0 + r) s[nf][r] = -INFINITY;
            }
        }
        float mt[4] = {-INFINITY, -INFINITY, -INFINITY, -INFINITY};
#pragma unroll
        for (int nf = 0; nf < 4; ++nf)
#pragma unroll
            for (int r = 0; r < 4; ++r) mt[r] = fmaxf(mt[r], s[nf][r]);
#pragma unroll
        for (int r = 0; r < 4; ++r)
#pragma unroll
            for (int off = 1; off < 16; off <<= 1)
                mt[r] = fmaxf(mt[r], __shfl_xor(mt[r], off));

        float corr[4];
#pragma unroll
        for (int r = 0; r < 4; ++r) {
            float mn = fmaxf(m[r], mt[r]);
            corr[r] = __expf(m[r] - mn);
            m[r] = mn;
        }
        float ps[4] = {0.f, 0.f, 0.f, 0.f};
#pragma unroll
        for (int nf = 0; nf < 4; ++nf)
#pragma unroll
            for (int r = 0; r < 4; ++r) {
                float p = __expf(s[nf][r] - m[r]);
                ps[r] += p;
                Ps[wid][lq * 4 + r][nf * 16 + lrow] = f2bf(p);
            }
#pragma unroll
        for (int r = 0; r < 4; ++r) {
#pragma unroll
            for (int off = 1; off < 16; off <<= 1) ps[r] += __shfl_xor(ps[r], off);
            l[r] = l[r] * corr[r] + ps[r];
        }
#pragma unroll
        for (int nf = 0; nf < 8; ++nf)
#pragma unroll
            for (int r = 0; r < 4; ++r) o[nf][r] *= corr[r];

        bf16x8 pa[2];
#pragma unroll
        for (int kf2 = 0; kf2 < 2; ++kf2)
            pa[kf2] = *(const bf16x8*)&Ps[wid][lrow][kf2 * 32 + lk];
        __builtin_amdgcn_s_setprio(1);
#pragma unroll
        for (int nf = 0; nf < 8; ++nf)
#pragma unroll
            for (int kf2 = 0; kf2 < 2; ++kf2)
                o[nf] = __builtin_amdgcn_mfma_f32_16x16x32_bf16(pa[kf2], vb[nf][kf2], o[nf], 0, 0, 0);
        __builtin_amdgcn_s_setprio(0);
    }

    if (nch == 1) {       // j <= 3: single chunk, write normalized
#pragma unroll
        for (int nf = 0; nf < 8; ++nf) {
            int col = nf * 16 + lrow;
#pragma unroll
            for (int r = 0; r < 4; ++r)
                out[((size_t)b * C_ + qrow0 + r) * H_ + col] = o[nf][r] / l[r];
        }
    } else {              // partial: O (bf16, unnormalized) + m,l
        const int slot = b * SLOTS_B + rr;
        unsigned short* po = PO + (size_t)slot * 64 * 128;
        const int rl0 = wid * 16 + lq * 4;
#pragma unroll
        for (int nf = 0; nf < 8; ++nf) {
            int col = nf * 16 + lrow;
#pragma unroll
            for (int r = 0; r < 4; ++r)
                po[(size_t)(rl0 + r) * 128 + col] = f2bf(o[nf][r]);
        }
        if (lrow == 0) {
            float* ml = ML + (size_t)slot * 128;
#pragma unroll
            for (int r = 0; r < 4; ++r) {
                ml[rl0 + r] = m[r];
                ml[64 + rl0 + r] = l[r];
            }
        }
    }
}

// ---------------- combine partials for j >= 4 --------------------------------
__global__ __launch_bounds__(256) void combine_kernel(const unsigned short* __restrict__ PO,
                                                      const float* __restrict__ ML,
                                                      float* __restrict__ out) {
    const int j = blockIdx.x + 4;
    const int b = blockIdx.y;
    const int q = j >> 2, s = j & 3;
    const int Cj = j + 2 * q * (q - 1) + s * q;
    const int nch = q + 1;
    const int base = b * SLOTS_B + Cj;
    const int row = threadIdx.x >> 2;
    const int colg = (threadIdx.x & 3) * 32;

    float mstar = -INFINITY;
    for (int c = 0; c < nch; ++c)
        mstar = fmaxf(mstar, ML[(size_t)(base + c) * 128 + row]);

    float denom = 0.f;
    float acc[32];
#pragma unroll
    for (int i = 0; i < 32; ++i) acc[i] = 0.f;

    for (int c = 0; c < nch; ++c) {
        float mc = ML[(size_t)(base + c) * 128 + row];
        float lc = ML[(size_t)(base + c) * 128 + 64 + row];
        float w = __expf(mc - mstar);
        denom += w * lc;
        const unsigned short* p = PO + (size_t)(base + c) * 64 * 128 + (size_t)row * 128 + colg;
#pragma unroll
        for (int k = 0; k < 4; ++k) {
            bf16x8 v = *(const bf16x8*)&p[k * 8];
#pragma unroll
            for (int e = 0; e < 8; ++e)
                acc[k * 8 + e] += w * bf2f(((unsigned short*)&v)[e]);
        }
    }
    float inv = 1.f / denom;
    float* op = out + ((size_t)b * C_ + j * 64 + row) * H_ + colg;
#pragma unroll
    for (int k = 0; k < 8; ++k) {
        float4 st = {acc[k * 4] * inv, acc[k * 4 + 1] * inv, acc[k * 4 + 2] * inv, acc[k * 4 + 3] * inv};
        *(float4*)&op[k * 4] = st;
    }
}

extern "C" void kernel_launch(void* const* d_in, const int* in_sizes, int n_in,
                              void* d_out, int out_size, void* d_ws, size_t ws_size,
                              hipStream_t stream) {
    const float* x  = (const float*)d_in[0];
    const float* Wq = (const float*)d_in[1];
    const float* Wk = (const float*)d_in[2];
    const float* Wv = (const float*)d_in[3];
    float* out = (float*)d_out;

    // ws layout (~31.4 MB total):
    unsigned short* WT  = (unsigned short*)d_ws;                       // 768 KB (H x E row-major, x3)
    unsigned short* QKV = WT + (size_t)3 * H_ * E_;                    // 12 MB (Q, K, V^T)
    unsigned short* PO  = QKV + (size_t)3 * M_ * H_;                   // 18 MB partial O
    float*          ML  = (float*)(PO + (size_t)8 * SLOTS_B * 64 * 128); // 576 KB m,l

    wt_kernel<<<dim3(H_ * E_ / 256, 3), 256, 0, stream>>>(Wq, Wk, Wv, WT);
    proj_kernel<<<dim3(M_ / 128, 3), 256, 0, stream>>>(x, WT, QKV);
    attn_kernel<<<dim3(B_, SLOTS_B), 256, 0, stream>>>(QKV, PO, ML, out);
    combine_kernel<<<dim3(28, B_), 256, 0, stream>>>(PO, ML, out);
}

// Round 12
// 69.933 us; speedup vs baseline: 1.3866x; 1.3866x over previous
//
#include <hip/hip_runtime.h>
#include <hip/hip_bf16.h>
#include <stdint.h>

#define B_ 8
#define C_ 2048
#define E_ 1024
#define H_ 128
#define M_ (B_*C_)      // 16384 rows total
#define SLOTS_B 144     // chunks per batch: sum_j ceil((j+1)/4), j<32

typedef __attribute__((ext_vector_type(8))) short bf16x8;
typedef __attribute__((ext_vector_type(4))) float f32x4;

__device__ __forceinline__ unsigned short f2bf(float f) {
    union { float f; unsigned int u; } v; v.f = f;
    unsigned int u = v.u;
    u += 0x7fff + ((u >> 16) & 1);   // RNE
    return (unsigned short)(u >> 16);
}
__device__ __forceinline__ float bf2f(unsigned short u) {
    union { unsigned int i; float f; } v; v.i = ((unsigned int)u) << 16; return v.f;
}
// pack two floats -> two bf16 (round-half-up) in ONE v_perm + 2 adds
__device__ __forceinline__ unsigned int pack2bf(float lo, float hi) {
    union { float f; unsigned int u; } a, b; a.f = lo; b.f = hi;
    return __builtin_amdgcn_perm(b.u + 0x8000u, a.u + 0x8000u, 0x07060302);
}

#define GLOAD_LDS16(g, l) \
    __builtin_amdgcn_global_load_lds((const __attribute__((address_space(1))) void*)(g), \
                                     (__attribute__((address_space(3))) void*)(l), 16, 0, 0)

// -------- W -> fragment-ordered bf16: WT2[w][g*128 + h] = 16B granule -------
__global__ __launch_bounds__(256) void wt2_kernel(const float* __restrict__ Wq,
                                                  const float* __restrict__ Wk,
                                                  const float* __restrict__ Wv,
                                                  unsigned short* __restrict__ WT2) {
    int z = blockIdx.y;
    const float* W = (z == 0) ? Wq : (z == 1) ? Wk : Wv;
    unsigned short* o = WT2 + (size_t)z * H_ * E_;
    int gid = blockIdx.x * 256 + threadIdx.x;   // over (E_/8)*H_ = 16384 granules
    int g = gid >> 7, h = gid & 127;
    unsigned short t[8];
#pragma unroll
    for (int j = 0; j < 8; ++j)
        t[j] = f2bf(W[(size_t)(g * 8 + j) * H_ + h]);
    *(bf16x8*)&o[(size_t)(g * 128 + h) * 8] = *(const bf16x8*)t;
}

// ------ fused QKV projection (round-10 best): BM=32, x once ------------------
#define MF(a, b, c) __builtin_amdgcn_mfma_f32_16x16x32_bf16((a), (b), (c), 0, 0, 0)

#define ALOAD(S, T) { const float* xs_ = xrow + (T) * 64; \
    a##S##_0 = *(const float4*)xs_;  a##S##_1 = *(const float4*)(xs_ + 4); }

#define AWRITE(S, BUF) { \
    unsigned short t_[8] = {f2bf(a##S##_0.x), f2bf(a##S##_0.y), f2bf(a##S##_0.z), f2bf(a##S##_0.w), \
                            f2bf(a##S##_1.x), f2bf(a##S##_1.y), f2bf(a##S##_1.z), f2bf(a##S##_1.w)}; \
    *(bf16x8*)&As[BUF][arow][(ag ^ (arow & 7)) * 8] = *(const bf16x8*)t_; }

#define BLOAD(S, T) { const unsigned short* wp_ = wbase + (size_t)(T) * 8192; \
    b##S##0  = *(const bf16x8*)(wp_);            b##S##1  = *(const bf16x8*)(wp_ + 128); \
    b##S##2  = *(const bf16x8*)(wp_ + 4096);     b##S##3  = *(const bf16x8*)(wp_ + 4224); \
    b##S##4  = *(const bf16x8*)(wp_ + 131072);   b##S##5  = *(const bf16x8*)(wp_ + 131200); \
    b##S##6  = *(const bf16x8*)(wp_ + 135168);   b##S##7  = *(const bf16x8*)(wp_ + 135296); \
    b##S##8  = *(const bf16x8*)(wp_ + 262144);   b##S##9  = *(const bf16x8*)(wp_ + 262272); \
    b##S##10 = *(const bf16x8*)(wp_ + 266240);   b##S##11 = *(const bf16x8*)(wp_ + 266368); }

#define COMPUTE(BUF, S) { \
    bf16x8 af00 = *(const bf16x8*)&As[BUF][ra0][(lq ^ (ra0 & 7)) * 8]; \
    bf16x8 af10 = *(const bf16x8*)&As[BUF][ra1][(lq ^ (ra1 & 7)) * 8]; \
    acc[0][0][0] = MF(af00, b##S##0, acc[0][0][0]);  acc[0][1][0] = MF(af10, b##S##0, acc[0][1][0]); \
    acc[0][0][1] = MF(af00, b##S##1, acc[0][0][1]);  acc[0][1][1] = MF(af10, b##S##1, acc[0][1][1]); \
    acc[1][0][0] = MF(af00, b##S##4, acc[1][0][0]);  acc[1][1][0] = MF(af10, b##S##4, acc[1][1][0]); \
    acc[1][0][1] = MF(af00, b##S##5, acc[1][0][1]);  acc[1][1][1] = MF(af10, b##S##5, acc[1][1][1]); \
    acc[2][0][0] = MF(af00, b##S##8, acc[2][0][0]);  acc[2][1][0] = MF(af10, b##S##8, acc[2][1][0]); \
    acc[2][0][1] = MF(af00, b##S##9, acc[2][0][1]);  acc[2][1][1] = MF(af10, b##S##9, acc[2][1][1]); \
    bf16x8 af01 = *(const bf16x8*)&As[BUF][ra0][((4 + lq) ^ (ra0 & 7)) * 8]; \
    bf16x8 af11 = *(const bf16x8*)&As[BUF][ra1][((4 + lq) ^ (ra1 & 7)) * 8]; \
    acc[0][0][0] = MF(af01, b##S##2, acc[0][0][0]);  acc[0][1][0] = MF(af11, b##S##2, acc[0][1][0]); \
    acc[0][0][1] = MF(af01, b##S##3, acc[0][0][1]);  acc[0][1][1] = MF(af11, b##S##3, acc[0][1][1]); \
    acc[1][0][0] = MF(af01, b##S##6, acc[1][0][0]);  acc[1][1][0] = MF(af11, b##S##6, acc[1][1][0]); \
    acc[1][0][1] = MF(af01, b##S##7, acc[1][0][1]);  acc[1][1][1] = MF(af11, b##S##7, acc[1][1][1]); \
    acc[2][0][0] = MF(af01, b##S##10, acc[2][0][0]); acc[2][1][0] = MF(af11, b##S##10, acc[2][1][0]); \
    acc[2][0][1] = MF(af01, b##S##11, acc[2][0][1]); acc[2][1][1] = MF(af11, b##S##11, acc[2][1][1]); }

#define STEP_E(K) { __syncthreads(); \
    if ((K) < 15) { ALOAD(O, (K)+1); BLOAD(O, (K)+1); } \
    COMPUTE((K)&1, E); \
    if ((K) < 15) AWRITE(O, ((K)+1)&1); }

#define STEP_O(K) { __syncthreads(); \
    if ((K) < 15) { ALOAD(E, (K)+1); BLOAD(E, (K)+1); } \
    COMPUTE((K)&1, O); \
    if ((K) < 15) AWRITE(E, ((K)+1)&1); }

__global__ __launch_bounds__(256) void proj_kernel(const float* __restrict__ x,
                                                   const unsigned short* __restrict__ WT2,
                                                   unsigned short* __restrict__ QKV) {
    __shared__ __align__(16) unsigned short As[2][32][64];    // 8 KB dbuf, XOR-swz

    const int tid = threadIdx.x;
    const int wid = tid >> 6, lane = tid & 63;
    const int lrow = lane & 15, lq = lane >> 4;
    const int wcol = wid * 32;
    const int row0 = blockIdx.x * 32;

    const int arow = tid >> 3;
    const int ag = tid & 7;
    const float* xrow = x + (size_t)(row0 + arow) * E_ + ag * 8;
    const int ra0 = lrow, ra1 = 16 + lrow;
    const unsigned short* wbase = WT2 + (size_t)(lq * 128 + wcol + lrow) * 8;

    f32x4 acc[3][2][2];
#pragma unroll
    for (int w = 0; w < 3; ++w)
#pragma unroll
        for (int mi = 0; mi < 2; ++mi)
#pragma unroll
            for (int ni = 0; ni < 2; ++ni) acc[w][mi][ni] = (f32x4){0.f, 0.f, 0.f, 0.f};

    float4 aE_0, aE_1, aO_0, aO_1;
    bf16x8 bE0, bE1, bE2, bE3, bE4, bE5, bE6, bE7, bE8, bE9, bE10, bE11;
    bf16x8 bO0, bO1, bO2, bO3, bO4, bO5, bO6, bO7, bO8, bO9, bO10, bO11;

    ALOAD(E, 0); BLOAD(E, 0);
    AWRITE(E, 0);

    STEP_E(0)  STEP_O(1)  STEP_E(2)  STEP_O(3)
    STEP_E(4)  STEP_O(5)  STEP_E(6)  STEP_O(7)
    STEP_E(8)  STEP_O(9)  STEP_E(10) STEP_O(11)
    STEP_E(12) STEP_O(13) STEP_E(14) STEP_O(15)

#pragma unroll
    for (int w = 0; w < 2; ++w) {
        const float qs = (w == 0) ? 0.03125f : 1.0f;   // fold 1/sqrt(E) into Q
        unsigned short* outp = QKV + (size_t)w * M_ * H_;
#pragma unroll
        for (int mi = 0; mi < 2; ++mi) {
            int r0 = row0 + mi * 16 + lq * 4;
#pragma unroll
            for (int ni = 0; ni < 2; ++ni) {
                int col = wcol + ni * 16 + lrow;
#pragma unroll
                for (int r = 0; r < 4; ++r)
                    outp[(size_t)(r0 + r) * H_ + col] = f2bf(acc[w][mi][ni][r] * qs);
            }
        }
    }
    {
        unsigned short* vt = QKV + (size_t)2 * M_ * H_;
        int b = row0 / C_;
        int cbase = row0 % C_;
#pragma unroll
        for (int mi = 0; mi < 2; ++mi) {
            int c0 = cbase + mi * 16 + lq * 4;
#pragma unroll
            for (int ni = 0; ni < 2; ++ni) {
                int h = wcol + ni * 16 + lrow;
                __align__(8) unsigned short p[4] = {f2bf(acc[2][mi][ni][0]), f2bf(acc[2][mi][ni][1]),
                                                    f2bf(acc[2][mi][ni][2]), f2bf(acc[2][mi][ni][3])};
                *(uint2*)&vt[((size_t)b * H_ + h) * C_ + c0] = *(const uint2*)p;
            }
        }
    }
}

// ---------------- split-KV flash attention, swapped-QK lane-local softmax ----
// grid (B, 144): blockIdx.x = batch -> XCD = b.
// K staged with row bit-permutation pi so each lane's P values are exactly its
// PV A-fragment: pi(R) = [b4 b3 b2 b5 b1 b0].
__global__ __launch_bounds__(256) void attn_kernel(const unsigned short* __restrict__ QKV,
                                                   unsigned short* __restrict__ PO,
                                                   float* __restrict__ ML,
                                                   float* __restrict__ out) {
    __shared__ __align__(16) unsigned short Ks[2][64][128];
    __shared__ __align__(16) unsigned short Vt[2][128][64];

    const unsigned short* Q  = QKV;
    const unsigned short* K  = QKV + (size_t)M_ * H_;
    const unsigned short* VT = QKV + (size_t)2 * M_ * H_;

    const int tid = threadIdx.x, wid = tid >> 6, lane = tid & 63;
    const int lrow = lane & 15, lq = lane >> 4, lk = lq * 8;
    const int b = blockIdx.x;
    const int rr = blockIdx.y;

    int j = 0;
#pragma unroll
    for (int jj = 1; jj < 32; ++jj) {
        int q = jj >> 2, s = jj & 3;
        if (jj + 2 * q * (q - 1) + s * q <= rr) j = jj;
    }
    const int qj = j >> 2, sj = j & 3;
    const int Cj = j + 2 * qj * (qj - 1) + sj * qj;
    const int c = rr - Cj;
    const int nch = qj + 1;
    const int t0 = c * 4;
    const int t1 = min(t0 + 4, j + 1);

    const int q0w = j * 64 + wid * 16;
    const unsigned short* Kb  = K  + (size_t)b * C_ * H_;
    const unsigned short* VTb = VT + (size_t)b * H_ * C_;
    const int qabs = q0w + lrow;        // this lane's q row (softmax space)

    const int krow = tid >> 4, kg = tid & 15;
    const int vrow = tid >> 3, vg = tid & 7;

    bf16x8 qf[4];
#pragma unroll
    for (int kf = 0; kf < 4; ++kf)
        qf[kf] = *(const bf16x8*)&Q[((size_t)b * C_ + q0w + lrow) * H_ + kf * 32 + lk];

    f32x4 o[8];
#pragma unroll
    for (int nf = 0; nf < 8; ++nf) o[nf] = (f32x4){0.f, 0.f, 0.f, 0.f};
    float m = -INFINITY, l = 0.f;       // scalar state for q = qabs

    auto STAGE = [&](int buf, int t) {
        const int kv0 = t * 64;
#pragma unroll
        for (int s = 0; s < 4; ++s) {
            int r = s * 16 + krow;      // LDS row
            int prow = ((r & 0x10) << 1) | ((r & 0x0C) << 1) | ((r & 0x20) >> 3) | (r & 3);
            GLOAD_LDS16(&Kb[(size_t)(kv0 + prow) * H_ + ((kg ^ (r & 15)) * 8)],
                        (char*)&Ks[buf][0][0] + s * 4096 + tid * 16);
        }
#pragma unroll
        for (int s = 0; s < 4; ++s) {
            int h = s * 32 + vrow;
            GLOAD_LDS16(&VTb[(size_t)h * C_ + kv0 + ((vg ^ (h & 7)) * 8)],
                        (char*)&Vt[buf][0][0] + s * 4096 + tid * 16);
        }
    };

    STAGE(0, t0);

    for (int t = t0; t < t1; ++t) {
        const int cur = (t - t0) & 1;
        __syncthreads();
        if (t + 1 < t1) STAGE(cur ^ 1, t + 1);

        const int kv0 = t * 64;
        f32x4 s[4];
        __builtin_amdgcn_s_setprio(1);
#pragma unroll
        for (int nf = 0; nf < 4; ++nf) {
            s[nf] = (f32x4){0.f, 0.f, 0.f, 0.f};
            const int rk = nf * 16 + lrow;
#pragma unroll
            for (int kf = 0; kf < 4; ++kf) {
                bf16x8 kb = *(const bf16x8*)&Ks[cur][rk][((kf * 4 + lq) ^ (rk & 15)) * 8];
                s[nf] = __builtin_amdgcn_mfma_f32_16x16x32_bf16(kb, qf[kf], s[nf], 0, 0, 0); // SWAPPED
            }
        }
        __builtin_amdgcn_s_setprio(0);
        bf16x8 vb[8][2];
#pragma unroll
        for (int nf = 0; nf < 8; ++nf) {
            const int h = nf * 16 + lrow;
#pragma unroll
            for (int kf2 = 0; kf2 < 2; ++kf2)
                vb[nf][kf2] = *(const bf16x8*)&Vt[cur][h][((kf2 * 4 + lq) ^ (h & 7)) * 8];
        }

        // lane holds S[kv][q=qabs]; kv = kv0 + (nf&1)*32 + lq*8 + (nf>>1)*4 + r
        if (t == j) {
#pragma unroll
            for (int nf = 0; nf < 4; ++nf) {
                int kvb = kv0 + ((nf & 1) << 5) + (lq << 3) + ((nf >> 1) << 2);
#pragma unroll
                for (int r = 0; r < 4; ++r)
                    if (kvb + r > qabs) s[nf][r] = -INFINITY;
            }
        }
        // in-lane max over 16 + 2-hop cross-lq reduce
        float mt = s[0][0];
#pragma unroll
        for (int nf = 0; nf < 4; ++nf)
#pragma unroll
            for (int r = 0; r < 4; ++r) mt = fmaxf(mt, s[nf][r]);
        mt = fmaxf(mt, __shfl_xor(mt, 16));
        mt = fmaxf(mt, __shfl_xor(mt, 32));

        float mn = fmaxf(m, mt);
        float corr = __expf(m - mn);    // first tile: exp(-inf)=0
        m = mn;

        float p[4][4];
        float ps = 0.f;
#pragma unroll
        for (int nf = 0; nf < 4; ++nf)
#pragma unroll
            for (int r = 0; r < 4; ++r) {
                float e = __expf(s[nf][r] - mn);   // masked -> 0
                p[nf][r] = e;
                ps += e;
            }
        ps += __shfl_xor(ps, 16);
        ps += __shfl_xor(ps, 32);
        l = l * corr + ps;

        // redistribute corr to D-row space (row q = lq*4+r)
        float corr4[4];
#pragma unroll
        for (int r = 0; r < 4; ++r)
            corr4[r] = __shfl(corr, (lane & 48) | (lq * 4 + r));
#pragma unroll
        for (int nf = 0; nf < 8; ++nf)
#pragma unroll
            for (int r = 0; r < 4; ++r) o[nf][r] *= corr4[r];

        // in-register P -> A-frag pack (permuted-K makes this exact)
        bf16x8 pa[2];
#pragma unroll
        for (int kf2 = 0; kf2 < 2; ++kf2) {
            union { unsigned int u[4]; bf16x8 v; } pk;
            pk.u[0] = pack2bf(p[kf2][0],     p[kf2][1]);
            pk.u[1] = pack2bf(p[kf2][2],     p[kf2][3]);
            pk.u[2] = pack2bf(p[kf2 + 2][0], p[kf2 + 2][1]);
            pk.u[3] = pack2bf(p[kf2 + 2][2], p[kf2 + 2][3]);
            pa[kf2] = pk.v;
        }
        __builtin_amdgcn_s_setprio(1);
#pragma unroll
        for (int nf = 0; nf < 8; ++nf)
#pragma unroll
            for (int kf2 = 0; kf2 < 2; ++kf2)
                o[nf] = __builtin_amdgcn_mfma_f32_16x16x32_bf16(pa[kf2], vb[nf][kf2], o[nf], 0, 0, 0);
        __builtin_amdgcn_s_setprio(0);
    }

    // redistribute l (and m) from softmax space (q=lane&15) to D-row space
    float l4[4], m4[4];
#pragma unroll
    for (int r = 0; r < 4; ++r) {
        l4[r] = __shfl(l, (lane & 48) | (lq * 4 + r));
        m4[r] = __shfl(m, (lane & 48) | (lq * 4 + r));
    }
    const int qrow0 = q0w + lq * 4;

    if (nch == 1) {       // j <= 3: single chunk, write normalized
#pragma unroll
        for (int nf = 0; nf < 8; ++nf) {
            int col = nf * 16 + lrow;
#pragma unroll
            for (int r = 0; r < 4; ++r)
                out[((size_t)b * C_ + qrow0 + r) * H_ + col] = o[nf][r] / l4[r];
        }
    } else {              // partial: O (bf16, unnormalized) + m,l
        const int slot = b * SLOTS_B + rr;
        unsigned short* po = PO + (size_t)slot * 64 * 128;
        const int rl0 = wid * 16 + lq * 4;
#pragma unroll
        for (int nf = 0; nf < 8; ++nf) {
            int col = nf * 16 + lrow;
#pragma unroll
            for (int r = 0; r < 4; ++r)
                po[(size_t)(rl0 + r) * 128 + col] = f2bf(o[nf][r]);
        }
        if (lrow == 0) {
            float* ml = ML + (size_t)slot * 128;
#pragma unroll
            for (int r = 0; r < 4; ++r) {
                ml[rl0 + r] = m4[r];
                ml[64 + rl0 + r] = l4[r];
            }
        }
    }
}

// ---------------- combine partials for j >= 4 --------------------------------
__global__ __launch_bounds__(256) void combine_kernel(const unsigned short* __restrict__ PO,
                                                      const float* __restrict__ ML,
                                                      float* __restrict__ out) {
    const int j = blockIdx.x + 4;
    const int b = blockIdx.y;
    const int q = j >> 2, s = j & 3;
    const int Cj = j + 2 * q * (q - 1) + s * q;
    const int nch = q + 1;
    const int base = b * SLOTS_B + Cj;
    const int row = threadIdx.x >> 2;
    const int colg = (threadIdx.x & 3) * 32;

    float mstar = -INFINITY;
    for (int c = 0; c < nch; ++c)
        mstar = fmaxf(mstar, ML[(size_t)(base + c) * 128 + row]);

    float denom = 0.f;
    float acc[32];
#pragma unroll
    for (int i = 0; i < 32; ++i) acc[i] = 0.f;

    for (int c = 0; c < nch; ++c) {
        float mc = ML[(size_t)(base + c) * 128 + row];
        float lc = ML[(size_t)(base + c) * 128 + 64 + row];
        float w = __expf(mc - mstar);
        denom += w * lc;
        const unsigned short* p = PO + (size_t)(base + c) * 64 * 128 + (size_t)row * 128 + colg;
#pragma unroll
        for (int k = 0; k < 4; ++k) {
            bf16x8 v = *(const bf16x8*)&p[k * 8];
#pragma unroll
            for (int e = 0; e < 8; ++e)
                acc[k * 8 + e] += w * bf2f(((unsigned short*)&v)[e]);
        }
    }
    float inv = 1.f / denom;
    float* op = out + ((size_t)b * C_ + j * 64 + row) * H_ + colg;
#pragma unroll
    for (int k = 0; k < 8; ++k) {
        float4 st = {acc[k * 4] * inv, acc[k * 4 + 1] * inv, acc[k * 4 + 2] * inv, acc[k * 4 + 3] * inv};
        *(float4*)&op[k * 4] = st;
    }
}

extern "C" void kernel_launch(void* const* d_in, const int* in_sizes, int n_in,
                              void* d_out, int out_size, void* d_ws, size_t ws_size,
                              hipStream_t stream) {
    const float* x  = (const float*)d_in[0];
    const float* Wq = (const float*)d_in[1];
    const float* Wk = (const float*)d_in[2];
    const float* Wv = (const float*)d_in[3];
    float* out = (float*)d_out;

    unsigned short* WT2 = (unsigned short*)d_ws;                       // 768 KB
    unsigned short* QKV = WT2 + (size_t)3 * H_ * E_;                   // 12 MB (Q, K, V^T)
    unsigned short* PO  = QKV + (size_t)3 * M_ * H_;                   // 18 MB partial O
    float*          ML  = (float*)(PO + (size_t)8 * SLOTS_B * 64 * 128); // 576 KB m,l

    wt2_kernel<<<dim3(E_ / 8 * H_ / 256, 3), 256, 0, stream>>>(Wq, Wk, Wv, WT2);
    proj_kernel<<<dim3(M_ / 32), 256, 0, stream>>>(x, WT2, QKV);
    attn_kernel<<<dim3(B_, SLOTS_B), 256, 0, stream>>>(QKV, PO, ML, out);
    combine_kernel<<<dim3(28, B_), 256, 0, stream>>>(PO, ML, out);
}